// Round 1
// baseline (391.427 us; speedup 1.0000x reference)
//
#include <hip/hip_runtime.h>
#include <math.h>

// Problem constants (from reference): B=16384, DMODEL=64, NPTS=1323
#define BATCH   16384
#define DMODEL  64
#define NPTS    1323
#define ROW_F   (NPTS * 3)   // 3969 floats per dxyz row

// 1.5 * log(2*pi)
#define C_15LOG2PI 2.7568155996140194f

__device__ __forceinline__ float wave_reduce_sum64(float v) {
#pragma unroll
    for (int off = 32; off > 0; off >>= 1)
        v += __shfl_xor(v, off, 64);
    return v;
}

__device__ __forceinline__ float softplus_f(float x) {
    // x is a sigmoid output in (0,1): no overflow concerns
    return log1pf(expf(x));
}

__device__ __forceinline__ float sigmoid_f(float x) {
    return 1.0f / (1.0f + expf(-x));
}

__global__ __launch_bounds__(256) void mvn_profile_kernel(
    const float* __restrict__ rep,    // (B, 64)
    const float* __restrict__ dxyz,   // (B, NPTS, 3)
    const float* __restrict__ Wm,     // (3, 64)
    const float* __restrict__ bm,     // (3,)
    const float* __restrict__ Ws,     // (6, 64)
    const float* __restrict__ bs,     // (6,)
    float* __restrict__ out)          // (B, NPTS)
{
    const int row = blockIdx.x;
    const int tid = threadIdx.x;

    // params: m0,m1,m2, invL00, L10, invL11, L20, L21, invL22, c
    __shared__ float P[10];

    if (tid < 64) {
        const int l = tid;
        const float r = rep[(size_t)row * DMODEL + l];

        float d0 = r * Wm[0 * 64 + l];
        float d1 = r * Wm[1 * 64 + l];
        float d2 = r * Wm[2 * 64 + l];
        float s0 = r * Ws[0 * 64 + l];
        float s1 = r * Ws[1 * 64 + l];
        float s2 = r * Ws[2 * 64 + l];
        float s3 = r * Ws[3 * 64 + l];
        float s4 = r * Ws[4 * 64 + l];
        float s5 = r * Ws[5 * 64 + l];

        d0 = wave_reduce_sum64(d0);
        d1 = wave_reduce_sum64(d1);
        d2 = wave_reduce_sum64(d2);
        s0 = wave_reduce_sum64(s0);
        s1 = wave_reduce_sum64(s1);
        s2 = wave_reduce_sum64(s2);
        s3 = wave_reduce_sum64(s3);
        s4 = wave_reduce_sum64(s4);
        s5 = wave_reduce_sum64(s5);

        if (l == 0) {
            const float m0 = d0 + bm[0];
            const float m1 = d1 + bm[1];
            const float m2 = d2 + bm[2];

            const float t0 = sigmoid_f(s0 + bs[0]);
            const float t1 = sigmoid_f(s1 + bs[1]);
            const float t2 = sigmoid_f(s2 + bs[2]);
            const float t3 = sigmoid_f(s3 + bs[3]);
            const float t4 = sigmoid_f(s4 + bs[4]);
            const float t5 = sigmoid_f(s5 + bs[5]);

            const float L00 = softplus_f(t0);
            const float L10 = t1;
            const float L11 = softplus_f(t2);
            const float L20 = t3;
            const float L21 = t4;
            const float L22 = softplus_f(t5);

            P[0] = m0;
            P[1] = m1;
            P[2] = m2;
            P[3] = 1.0f / L00;
            P[4] = L10;
            P[5] = 1.0f / L11;
            P[6] = L20;
            P[7] = L21;
            P[8] = 1.0f / L22;
            P[9] = -(logf(L00) + logf(L11) + logf(L22)) - C_15LOG2PI;
        }
    }
    __syncthreads();

    const float m0   = P[0];
    const float m1   = P[1];
    const float m2   = P[2];
    const float iL00 = P[3];
    const float L10  = P[4];
    const float iL11 = P[5];
    const float L20  = P[6];
    const float L21  = P[7];
    const float iL22 = P[8];
    const float c    = P[9];

    const float* __restrict__ src = dxyz + (size_t)row * ROW_F;
    float* __restrict__ dst       = out  + (size_t)row * NPTS;

    for (int p = tid; p < NPTS; p += 256) {
        const float x = src[p * 3 + 0];
        const float y = src[p * 3 + 1];
        const float z = src[p * 3 + 2];

        const float e0 = x - m0;
        const float e1 = y - m1;
        const float e2 = z - m2;

        const float z0 = e0 * iL00;
        const float z1 = fmaf(-L10, z0, e1) * iL11;
        const float z2 = fmaf(-L21, z1, fmaf(-L20, z0, e2)) * iL22;

        const float maha = fmaf(z0, z0, fmaf(z1, z1, z2 * z2));
        dst[p] = __expf(fmaf(-0.5f, maha, c));
    }
}

extern "C" void kernel_launch(void* const* d_in, const int* in_sizes, int n_in,
                              void* d_out, int out_size, void* d_ws, size_t ws_size,
                              hipStream_t stream) {
    const float* rep  = (const float*)d_in[0];
    const float* dxyz = (const float*)d_in[1];
    const float* Wm   = (const float*)d_in[2];
    const float* bm   = (const float*)d_in[3];
    const float* Ws   = (const float*)d_in[4];
    const float* bs   = (const float*)d_in[5];
    // d_in[6] = num_planes (unused, always 3)
    float* out = (float*)d_out;

    mvn_profile_kernel<<<BATCH, 256, 0, stream>>>(rep, dxyz, Wm, bm, Ws, bs, out);
}